// Round 4
// baseline (293.808 us; speedup 1.0000x reference)
//
#include <hip/hip_runtime.h>
#include <stdint.h>

// B=8, C=4, H=W=1024, PATCH=16, DOWN=4 -> L=4096, L2=256, K=256
// att_gt[b,c,l,m]*4096 = sum_k ind[b,c,l,k] * cnt[b,c,k,m]  (exact ints <= 4096)
// i8 MFMA GEMM computed TRANSPOSED: D[m][l] = cnt^T * ind^T, so the C/D
// register dimension runs along m (att's contiguous axis) -> float4 epilogue.

#define BDIM 256

typedef int   v4i  __attribute__((ext_vector_type(4)));
typedef int   v16i __attribute__((ext_vector_type(16)));
typedef float v4f  __attribute__((ext_vector_type(4)));

// ---------------------------------------------------------------------------
// K1: cls[b][l][k] u8 class map in unfold layout. Thread = (b, h, wgrp):
// lane-consecutive wgrp -> 4 KB contiguous tgt reads per wave.
// Writes 16-B chunks at 256-B stride (8 MB total, L2 merges lines).
// Also zeroes d_out (harness re-poisons it each launch).
// ---------------------------------------------------------------------------
__global__ __launch_bounds__(BDIM) void cls_kernel(
    const int* __restrict__ tgt, uint8_t* __restrict__ cls,
    float* __restrict__ dout) {
  int id = blockIdx.x * BDIM + threadIdx.x;   // 0 .. 524287
  if (id == 0) *dout = 0.f;
  int b  = id >> 16;
  int h  = (id >> 6) & 1023;
  int wg = id & 63;
  const int* p = tgt + ((size_t)b << 20) + ((size_t)h << 10) + (wg << 4);
  uint32_t o[4];
#pragma unroll
  for (int i = 0; i < 4; ++i) {
    int4 v = *(const int4*)(p + (i << 2));
    o[i] = (uint32_t)v.x | ((uint32_t)v.y << 8) |
           ((uint32_t)v.z << 16) | ((uint32_t)v.w << 24);
  }
  int l  = ((h >> 4) << 6) | wg;
  int ky = h & 15;
  *(uint4*)(cls + ((size_t)b << 20) + ((size_t)l << 8) + (ky << 4)) =
      make_uint4(o[0], o[1], o[2], o[3]);
}

// ---------------------------------------------------------------------------
// K2: cntT[b][c][m][k] u8 counts (so cnt fragments are contiguous 16-B loads).
// Thread = pooled pixel (b, Y, X): counts classes of its 4x4 block via cls.
// ---------------------------------------------------------------------------
__global__ __launch_bounds__(BDIM) void cnt_kernel(
    const uint8_t* __restrict__ cls, uint8_t* __restrict__ cntT) {
  int id = blockIdx.x * BDIM + threadIdx.x;   // 0 .. 524287
  int b = id >> 16;
  int Y = (id >> 8) & 255;
  int X = id & 255;
  int l = ((Y >> 2) << 6) | (X >> 2);
  const uint8_t* p = cls + ((size_t)b << 20) + ((size_t)l << 8) +
                     ((Y & 3) << 6) + ((X & 3) << 2);
  uint32_t pc = 0;   // 4 packed u8 class counts (max 16 each)
#pragma unroll
  for (int dy = 0; dy < 4; ++dy) {
    uint32_t wv = *(const uint32_t*)(p + (dy << 4));
#pragma unroll
    for (int s = 0; s < 32; s += 8)
      pc += 1u << (((wv >> s) & 3u) << 3);
  }
  int m  = ((Y >> 4) << 4) | (X >> 4);
  int km = ((Y & 15) << 4) | (X & 15);
  size_t o = ((size_t)b << 18) | ((size_t)m << 8) | (size_t)km;
#pragma unroll
  for (int c = 0; c < 4; ++c)
    cntT[o + ((size_t)c << 16)] = (uint8_t)((pc >> (c << 3)) & 0xFFu);
}

// ---------------------------------------------------------------------------
// K3: per (b,c): D[m][l] = sum_k cnt[m][k] * ind[l][k] via mfma_i32_32x32x32_i8
// with OPERANDS SWAPPED (A=cnt, B=ind). C/D layout: col = lane&31 = l-offset,
// row = (reg&3) + 8*(reg>>2) + 4*(lane>>5) = m-offset. So per lane l is FIXED
// and acc[4q..4q+3] are 4 consecutive m -> float4 att loads, in-register MSE.
// Wave = 32-l strip x all 256 m. No LDS / barriers in the hot loop.
// ---------------------------------------------------------------------------
__global__ __launch_bounds__(BDIM) void gemm_kernel(
    const uint8_t* __restrict__ cls, const uint8_t* __restrict__ cntT,
    const float* __restrict__ att, float* __restrict__ dout) {
  __shared__ float wsum[4];
  const int t    = threadIdx.x;
  const int wv   = t >> 6, lane = t & 63;
  const int bc   = blockIdx.y;              // 0..31 : b=bc>>2, c=bc&3
  const int b    = bc >> 2, c = bc & 3;
  const int l0   = (blockIdx.x << 7) + (wv << 5);   // wave's 32-l strip
  const int lrow  = lane & 31;
  const int khalf = lane >> 5;

  // --- build the 8 ind fragments (B operand: col=l, k=khalf*16+j), VGPRs ---
  // classes < 4, so byte==c <=> both low bits of (byte^c) zero (exact SWAR;
  // the borrow-based zero-byte trick has false positives — round-2 bug).
  const uint32_t crep = (uint32_t)c * 0x01010101u;
  v4i ifr[8];
  const uint8_t* ibase = cls + ((size_t)b << 20) +
                         ((size_t)(l0 + lrow) << 8) + (khalf << 4);
#pragma unroll
  for (int kk = 0; kk < 8; ++kk) {
    uint4 raw = *(const uint4*)(ibase + (kk << 5));
    uint32_t r[4] = {raw.x, raw.y, raw.z, raw.w};
    v4i a;
#pragma unroll
    for (int i = 0; i < 4; ++i) {
      uint32_t x = r[i] ^ crep;                        // 0 where byte==c
      uint32_t nz = (x | (x >> 1)) & 0x01010101u;      // 1 where byte!=c
      a[i] = (int)(nz ^ 0x01010101u);                  // 1 where byte==c
    }
    ifr[kk] = a;
  }

  const uint8_t* cbase = cntT + ((size_t)bc << 16) + (khalf << 4);
  const float* attW = att + ((size_t)bc << 20) + ((size_t)(l0 + lrow) << 8);
  float lsum = 0.f;

#pragma unroll 1
  for (int mc = 0; mc < 8; ++mc) {
    // att tile for this lane: 4 float4 covering m = mc*32 + 4*khalf + 8q + j
    const float* ap = attW + (mc << 5) + (khalf << 2);
    v4f av[4];
#pragma unroll
    for (int q = 0; q < 4; ++q)
      av[q] = *(const v4f*)(ap + (q << 3));

    // A operand: cnt rows m = mc*32 + lrow
    const uint8_t* cb = cbase + ((size_t)((mc << 5) + lrow) << 8);
    v16i acc = {0,0,0,0,0,0,0,0,0,0,0,0,0,0,0,0};
#pragma unroll
    for (int kk = 0; kk < 8; ++kk) {
      uint4 raw = *(const uint4*)(cb + (kk << 5));
      v4i af;
      af[0] = (int)raw.x; af[1] = (int)raw.y;
      af[2] = (int)raw.z; af[3] = (int)raw.w;
      acc = __builtin_amdgcn_mfma_i32_32x32x32_i8(af, ifr[kk], acc, 0, 0, 0);
    }

#pragma unroll
    for (int q = 0; q < 4; ++q) {
#pragma unroll
      for (int j = 0; j < 4; ++j) {
        float d = fmaf((float)acc[(q << 2) + j], -1.f / 4096.f, av[q][j]);
        lsum = fmaf(d, d, lsum);
      }
    }
  }

  // --- block reduction -> one atomic ---
#pragma unroll
  for (int o = 32; o > 0; o >>= 1) lsum += __shfl_down(lsum, o, 64);
  if (lane == 0) wsum[wv] = lsum;
  __syncthreads();
  if (t == 0) {
    float s = (wsum[0] + wsum[1]) + (wsum[2] + wsum[3]);
    atomicAdd(dout, s * (1.f / 33554432.f));   // / (B*C*L*L2)
  }
}

extern "C" void kernel_launch(void* const* d_in, const int* in_sizes, int n_in,
                              void* d_out, int out_size, void* d_ws, size_t ws_size,
                              hipStream_t stream) {
  (void)in_sizes; (void)n_in; (void)out_size; (void)ws_size;
  const int*   tgt = (const int*)d_in[1];     // target (int32 on device)
  const float* att = (const float*)d_in[2];   // attentions
  float* dout      = (float*)d_out;
  uint8_t* cls     = (uint8_t*)d_ws;                    // 8 MB
  uint8_t* cntT    = (uint8_t*)d_ws + (8u << 20);       // 2 MB

  cls_kernel<<<dim3(524288 / BDIM), BDIM, 0, stream>>>(tgt, cls, dout);
  cnt_kernel<<<dim3(524288 / BDIM), BDIM, 0, stream>>>(cls, cntT);
  gemm_kernel<<<dim3(32, 32), BDIM, 0, stream>>>(cls, cntT, att, dout);
}